// Round 5
// baseline (83.907 us; speedup 1.0000x reference)
//
#include <hip/hip_runtime.h>
#include <cstdint>

#define BB 4
#define HH 2048
#define WW 2048
#define MAXT 21
#define BIGSQ 441   // MAXT^2
#define TROWS 106   // 64 output rows + 2*21 halo

static __device__ __forceinline__ uint32_t umin32(uint32_t a, uint32_t b) { return a < b ? a : b; }

// Fused chamfer: per 64x128 output tile, phase 1 computes horizontal capped
// nearest-obstacle distance (squared, packed u16) for 106 rows straight into
// LDS via the even/odd ballot + funnel-shift + sentinel-ctz scheme (validated
// R4). Phase 2 is the vertical relax + sqrt (validated R3). No intermediate
// HBM buffer: traffic = 64 MB in + 67 MB out.
__global__ __launch_bounds__(256) void fused(const int* __restrict__ in,
                                             float* __restrict__ out) {
    __shared__ uint16_t s[TROWS][128];   // 27136 B
    const int tid  = threadIdx.x;
    const int lane = tid & 63;
    const int w    = tid >> 6;
    const int x0   = blockIdx.x << 7;
    const int y0   = blockIdx.y << 6;
    const int b    = blockIdx.z;
    const long long base = (long long)b * HH * WW;
    const int li   = 63 - lane;
    const int hl2  = (lane & 31) << 1;
    const bool hasL = (x0 > 0);
    const bool hasR = (x0 + 128 < WW);

    // ---- Phase 1: horizontal pass -> LDS (dh^2 packed u16, lane owns px 2l,2l+1) ----
    for (int r = w; r < TROWS; r += 4) {
        const int gy = y0 - 21 + r;
        uint32_t pk;
        if (gy >= 0 && gy < HH) {
            const int* rp = in + base + (long long)gy * WW;
            uint2 uc = *(const uint2*)(rp + x0 + (lane << 1));
            unsigned long long b0c = __ballot(uc.x != 0);
            unsigned long long b1c = __ballot(uc.y != 0);
            unsigned long long b0p = 0, b1p = 0, b0n = 0, b1n = 0;
            if (hasL) {   // left halo px x0-64..x0-1 = pairs 32..63 of prev chunk
                uint2 hl = *(const uint2*)(rp + x0 - 64 + hl2);
                b0p = __ballot(lane < 32 && hl.x != 0) << 32;
                b1p = __ballot(lane < 32 && hl.y != 0) << 32;
            }
            if (hasR) {   // right halo px x0+128..x0+191 = pairs 0..31 of next chunk
                uint2 hr = *(const uint2*)(rp + x0 + 128 + hl2);
                b0n = __ballot(lane < 32 && hr.x != 0);
                b1n = __ballot(lane < 32 && hr.y != 0);
            }

            // reversed-space masks with phase swap: RB_m = brev(B_{1-m})
            unsigned long long rb0c = __brevll(b1c), rb1c = __brevll(b0c);
            unsigned long long rb0p = __brevll(b1p), rb1p = __brevll(b0p);

            unsigned long long S0  = (b0c >> lane) | ((b0n << 1) << li);
            unsigned long long S1  = (b1c >> lane) | ((b1n << 1) << li);
            unsigned long long SL0 = (rb0c >> li)  | ((rb0p << 1) << lane);
            unsigned long long SL1 = (rb1c >> li)  | ((rb1p << 1) << lane);

            const uint32_t SEN = 1u << 11;  // t=11 -> d>=22 -> clamps to 21
            uint32_t s0 = (uint32_t)S0, s1 = (uint32_t)S1;
            uint32_t l0 = (uint32_t)SL0, l1 = (uint32_t)SL1;
            int t_s0  = __builtin_ctz(s0 | SEN);
            int t_s1  = __builtin_ctz(s1 | SEN);
            int t_s0s = __builtin_ctz((s0 >> 1) | SEN);
            int t_l0  = __builtin_ctz(l0 | SEN);
            int t_l1  = __builtin_ctz(l1 | SEN);
            int t_l0s = __builtin_ctz((l0 >> 1) | SEN);

            int d0 = min(min(2 * t_s0, 2 * t_s1 + 1), min(2 * t_l1, 2 * t_l0s + 1));
            int d1 = min(min(2 * t_s1, 2 * t_s0s + 1), min(2 * t_l0, 2 * t_l1 + 1));
            d0 = min(d0, MAXT);
            d1 = min(d1, MAXT);
            pk = (uint32_t)(d0 * d0) | ((uint32_t)(d1 * d1) << 16);
        } else {
            pk = BIGSQ | (BIGSQ << 16);     // out-of-image rows never win
        }
        *(uint32_t*)&s[r][lane << 1] = pk;
    }
    __syncthreads();

    // ---- Phase 2: vertical relax + sqrt (lane owns 4 adjacent cols) ----
    const int cg = (lane & 31) << 2;
    const int ro = lane >> 5;
    for (int k = 0; k < 8; ++k) {
        const int j  = (w << 4) + (k << 1) + ro;
        const int yl = 21 + j;

        uint2 q = *(const uint2*)&s[yl][cg];
        uint32_t v0 = q.x & 0xffff, v1 = q.x >> 16;
        uint32_t v2 = q.y & 0xffff, v3 = q.y >> 16;

        for (int d = 1; d <= MAXT; ++d) {
            const uint32_t dd = (uint32_t)(d * d);
            uint32_t h  = v0 > v1 ? v0 : v1;
            uint32_t h2 = v2 > v3 ? v2 : v3;
            h = h > h2 ? h : h2;
            if (__all(dd >= h)) break;   // further candidates >= d^2 >= current val
            uint2 a  = *(const uint2*)&s[yl - d][cg];
            uint2 bq = *(const uint2*)&s[yl + d][cg];
            const uint32_t dd2 = dd * 0x10001u;   // packed u16 add, no carry (<= 882)
            uint32_t A0 = a.x + dd2, A1 = a.y + dd2;
            uint32_t B0 = bq.x + dd2, B1 = bq.y + dd2;
            v0 = umin32(v0, umin32(A0 & 0xffff, B0 & 0xffff));
            v1 = umin32(v1, umin32(A0 >> 16,    B0 >> 16));
            v2 = umin32(v2, umin32(A1 & 0xffff, B1 & 0xffff));
            v3 = umin32(v3, umin32(A1 >> 16,    B1 >> 16));
        }

        float4 o;
        o.x = sqrtf((float)v0);
        o.y = sqrtf((float)v1);
        o.z = sqrtf((float)v2);
        o.w = sqrtf((float)v3);
        *(float4*)&out[base + (long long)(y0 + j) * WW + x0 + cg] = o;
    }
}

extern "C" void kernel_launch(void* const* d_in, const int* in_sizes, int n_in,
                              void* d_out, int out_size, void* d_ws, size_t ws_size,
                              hipStream_t stream) {
    const int* unt = (const int*)d_in[0];
    float* out     = (float*)d_out;
    fused<<<dim3(WW / 128, HH / 64, BB), 256, 0, stream>>>(unt, out);
}

// Round 7
// 37.993 us; speedup vs baseline: 2.2085x; 2.2085x over previous
//
#include <hip/hip_runtime.h>
#include <cstdint>

#define BB 4
#define HH 2048
#define WW 2048
#define MAXT 21
#define BIGSQ 441        // MAXT^2
#define SEN (1u << 6)    // sentinel bit: quad-dist t=6 -> d>=24 -> clamps to 21

typedef float floatx4 __attribute__((ext_vector_type(4)));

static __device__ __forceinline__ uint32_t umin32(uint32_t a, uint32_t b) { return a < b ? a : b; }
static __device__ __forceinline__ int imin(int a, int b) { return a < b ? a : b; }

// ---------------- Pass A: horizontal capped nearest-obstacle distance ----------------
// One wave = one full row (2048 px), uint4 loads (16 B = 4 px per lane).
// Quad-phase ballot scheme: superchunk = 256 px; mask B_k bit l = obstacle at
// px 256j + 4l + k. Funnel-aligned masks (right: quads l+t; left: brev -> quads
// l-t), sentinel-capped ctz, then per-subpixel m combine via prefix/suffix mins:
//   right_m = min( suffmin_{k>=m} a_k, prefmin_{k<m} b_k ) - m,
//     a_k = 4*ctz(S_k)+k, b_k = 4*ctz(S_k>>1)+4+k
//   left_m  = m + min( prefmin_{k<=m} c_k, suffmin_{k>m} e_k ),
//     c_k = 4*ctz(SL_k)-k, e_k = 4*ctz(SL_k>>1)+4-k
__global__ __launch_bounds__(256) void hpass(const int* __restrict__ in,
                                             uint8_t* __restrict__ dh) {
    const int tid  = threadIdx.x;
    const int lane = tid & 63;
    const int w    = tid >> 6;
    const int row  = (blockIdx.x << 2) + w;   // 4 rows per block; rows never cross batches
    const long long ro = (long long)row * WW;
    const int* rp = in + ro;
    const int li = 63 - lane;

    uint4 q[8];
    #pragma unroll
    for (int j = 0; j < 8; ++j)
        q[j] = *(const uint4*)(rp + (j << 8) + (lane << 2));

    unsigned long long Bc[4], Bn[4], rbc[4], rbp[4];
    #pragma unroll
    for (int k = 0; k < 4; ++k) rbp[k] = 0;
    Bc[0] = __ballot(q[0].x != 0);
    Bc[1] = __ballot(q[0].y != 0);
    Bc[2] = __ballot(q[0].z != 0);
    Bc[3] = __ballot(q[0].w != 0);
    #pragma unroll
    for (int k = 0; k < 4; ++k) rbc[k] = __brevll(Bc[k]);

    #pragma unroll
    for (int j = 0; j < 8; ++j) {
        if (j < 7) {
            Bn[0] = __ballot(q[j + 1].x != 0);
            Bn[1] = __ballot(q[j + 1].y != 0);
            Bn[2] = __ballot(q[j + 1].z != 0);
            Bn[3] = __ballot(q[j + 1].w != 0);
        } else {
            Bn[0] = Bn[1] = Bn[2] = Bn[3] = 0;
        }

        int a[4], b[4], c[4], e[4];
        #pragma unroll
        for (int k = 0; k < 4; ++k) {
            unsigned long long S  = (Bc[k] >> lane) | ((Bn[k] << 1) << li);
            unsigned long long SL = (rbc[k] >> li)  | ((rbp[k] << 1) << lane);
            uint32_t s  = (uint32_t)S;
            uint32_t sl = (uint32_t)SL;
            a[k] = 4 * __builtin_ctz(s | SEN) + k;
            b[k] = 4 * __builtin_ctz((s >> 1) | SEN) + 4 + k;
            c[k] = 4 * __builtin_ctz(sl | SEN) - k;
            e[k] = 4 * __builtin_ctz((sl >> 1) | SEN) + 4 - k;
        }
        const int A3 = a[3], A2 = imin(a[2], A3), A1 = imin(a[1], A2), A0 = imin(a[0], A1);
        const int B0 = b[0], B1 = imin(B0, b[1]), B2 = imin(B1, b[2]);
        const int C0 = c[0], C1 = imin(C0, c[1]), C2 = imin(C1, c[2]), C3 = imin(C2, c[3]);
        const int E3 = e[3], E2 = imin(e[2], E3), E1 = imin(e[1], E2);

        int d0 = imin(imin(A0,           imin(C0, E1)    ), MAXT);
        int d1 = imin(imin(imin(A1, B0) - 1, imin(C1, E2) + 1), MAXT);
        int d2 = imin(imin(imin(A2, B1) - 2, imin(C2, E3) + 2), MAXT);
        int d3 = imin(imin(imin(A3, B2) - 3, C3 + 3          ), MAXT);

        uint32_t pk = (uint32_t)d0 | ((uint32_t)d1 << 8) | ((uint32_t)d2 << 16) | ((uint32_t)d3 << 24);
        *(uint32_t*)(dh + ro + (j << 8) + (lane << 2)) = pk;

        #pragma unroll
        for (int k = 0; k < 4; ++k) {
            rbp[k] = rbc[k];
            Bc[k]  = Bn[k];
            rbc[k] = __brevll(Bn[k]);
        }
    }
}

// ---------------- Pass B: vertical relax + sqrt ----------------
// 128x64 output tile, LDS dh^2 (u16) 106 rows. uint4 staging loads (16 px/lane),
// packed-u16 relax (validated R3), nontemporal float4 output stores.
// XCD-chunked block swizzle: vertically-adjacent tiles share an XCD's L2
// so the 21-row dh halo re-reads are L2 hits.
__global__ __launch_bounds__(256) void vpass(const uint8_t* __restrict__ dh,
                                             float* __restrict__ out) {
    __shared__ uint16_t s[106][128];   // 27136 B
    const int tid = threadIdx.x;
    const int bid = blockIdx.x;                   // 2048 blocks, 2048 % 8 == 0
    const int swz = (bid & 7) * 256 + (bid >> 3); // bijective XCD chunking
    const int x0  = (swz & 15) << 7;
    const int y0  = ((swz >> 4) & 31) << 6;
    const int b   = swz >> 9;
    const long long base = (long long)b * HH * WW;

    // stage: 16 dh bytes per lane-iter -> 16 squared u16 -> two b128 LDS writes
    for (int i = tid; i < 106 * 8; i += 256) {
        const int r   = i >> 3;
        const int c16 = (i & 7) << 4;
        const int gy  = y0 - 21 + r;
        uint4 pk0, pk1;
        if (gy >= 0 && gy < HH) {
            const uint8_t* p = dh + base + (long long)gy * WW + x0 + c16;
            uint4 u = *(const uint4*)p;
            #pragma unroll
            for (int h = 0; h < 4; ++h) {
                uint32_t word = (&u.x)[h];
                uint32_t e0 = word & 0xff, e1 = (word >> 8) & 0xff;
                uint32_t e2 = (word >> 16) & 0xff, e3 = word >> 24;
                uint32_t lo = (e0 * e0) | ((e1 * e1) << 16);
                uint32_t hi = (e2 * e2) | ((e3 * e3) << 16);
                if (h < 2) { (&pk0.x)[h * 2] = lo; (&pk0.x)[h * 2 + 1] = hi; }
                else       { (&pk1.x)[(h - 2) * 2] = lo; (&pk1.x)[(h - 2) * 2 + 1] = hi; }
            }
        } else {
            pk0.x = pk0.y = pk0.z = pk0.w = BIGSQ | (BIGSQ << 16);
            pk1 = pk0;
        }
        *(uint4*)&s[r][c16]     = pk0;
        *(uint4*)&s[r][c16 + 8] = pk1;
    }
    __syncthreads();

    const int lane = tid & 63;
    const int w    = tid >> 6;
    const int cg   = (lane & 31) << 2;   // 4 adjacent cols per lane
    const int ro   = lane >> 5;          // row offset 0/1
    for (int k = 0; k < 8; ++k) {
        const int j  = (w << 4) + (k << 1) + ro;
        const int yl = 21 + j;

        uint2 q = *(const uint2*)&s[yl][cg];
        uint32_t v0 = q.x & 0xffff, v1 = q.x >> 16;
        uint32_t v2 = q.y & 0xffff, v3 = q.y >> 16;

        for (int d = 1; d <= MAXT; ++d) {
            const uint32_t dd = (uint32_t)(d * d);
            uint32_t h  = v0 > v1 ? v0 : v1;
            uint32_t h2 = v2 > v3 ? v2 : v3;
            h = h > h2 ? h : h2;
            if (__all(dd >= h)) break;   // further candidates >= d^2 >= current val
            uint2 a  = *(const uint2*)&s[yl - d][cg];
            uint2 bq = *(const uint2*)&s[yl + d][cg];
            const uint32_t dd2 = dd * 0x10001u;   // packed u16 add, no carry (<= 882)
            uint32_t A0 = a.x + dd2, A1 = a.y + dd2;
            uint32_t B0 = bq.x + dd2, B1 = bq.y + dd2;
            v0 = umin32(v0, umin32(A0 & 0xffff, B0 & 0xffff));
            v1 = umin32(v1, umin32(A0 >> 16,    B0 >> 16));
            v2 = umin32(v2, umin32(A1 & 0xffff, B1 & 0xffff));
            v3 = umin32(v3, umin32(A1 >> 16,    B1 >> 16));
        }

        floatx4 o;
        o.x = sqrtf((float)v0);
        o.y = sqrtf((float)v1);
        o.z = sqrtf((float)v2);
        o.w = sqrtf((float)v3);
        floatx4* op = (floatx4*)&out[base + (long long)(y0 + j) * WW + x0 + cg];
        __builtin_nontemporal_store(o, op);
    }
}

extern "C" void kernel_launch(void* const* d_in, const int* in_sizes, int n_in,
                              void* d_out, int out_size, void* d_ws, size_t ws_size,
                              hipStream_t stream) {
    const int* unt = (const int*)d_in[0];
    uint8_t* dh    = (uint8_t*)d_ws;             // BB*HH*WW bytes = 16.7 MB scratch
    float* out     = (float*)d_out;

    hpass<<<dim3(BB * HH / 4), 256, 0, stream>>>(unt, dh);
    vpass<<<dim3(WW / 128 * HH / 64 * BB), 256, 0, stream>>>(dh, out);
}